// Round 5
// baseline (196.995 us; speedup 1.0000x reference)
//
#include <hip/hip_runtime.h>
#include <hip/hip_bf16.h>
#include <math.h>

#define NSRC 50000
#define NTGT 50000
#define NTOT 100000
#define NEDGE 800000
#define DIM 128

#define NBUCK 782       // buckets of 64 targets (49999>>6 = 781)
#define BCAP 1536       // max edges/bucket (mean 1024, sigma 32 -> +16 sigma)
#define BPAD 16         // bcnt stride (ints): one 64B line per bucket counter
#define BLK 512         // 8 waves per block
#define EPT 4           // edges per thread in partition (512*4 = 2048)
#define EPB 2048        // edges per partition block
#define PBLK 391        // ceil(800000 / 2048)
#define GEMM_GRID 782   // ceil(100000 / 128) : 128 nodes per gemm block

typedef __attribute__((ext_vector_type(8))) short short8;
typedef __attribute__((ext_vector_type(4))) float float4v;

union U8 { short8 s; uint4 u; };

__device__ __forceinline__ unsigned short f2bf(float f) {
    unsigned u = __float_as_uint(f);
    unsigned r = (u + 0x7FFFu + ((u >> 16) & 1u)) >> 16;  // RNE
    return (unsigned short)r;
}
__device__ __forceinline__ float bf2f(unsigned us) {
    return __uint_as_float(us << 16);
}
// packed RNE f32x2 -> bf16x2 (v_cvt_pk_bf16_f32)
__device__ __forceinline__ unsigned pkbf(float lo, float hi) {
    __hip_bfloat162 b = __float22bfloat162_rn(make_float2(lo, hi));
    return *(unsigned*)&b;
}

// ---------------- prep: W -> Wt (bf16, MFMA-fragment order) + zero bcnt ---
// Wt linear idx = ((t*4+s)*64 + lane)*8 + j  ->  W[(s*32+qd*8+j)][t*16+nl]
__global__ __launch_bounds__(256) void k_prep(const float* __restrict__ W,
                                              unsigned short* __restrict__ Wt,
                                              int* __restrict__ bcnt) {
    int i = blockIdx.x * 256 + threadIdx.x;  // grid = 64 blocks -> i < 16384
    if (i < NBUCK * BPAD) bcnt[i] = 0;
    int j = i & 7, lane = (i >> 3) & 63, ts = i >> 9;
    int t = ts >> 2, s = ts & 3;
    int nl = lane & 15, qd = lane >> 4;
    Wt[i] = f2bf(W[(s * 32 + qd * 8 + j) * DIM + (t * 16 + nl)]);
}

// ---------------- partition: edges -> 64-target buckets -------------------
// packed entry: row (16b) | c_local (6b in bits 16..21)
__global__ __launch_bounds__(BLK) void k_part(const int* __restrict__ row,
                                              const int* __restrict__ col,
                                              int* __restrict__ bcnt,
                                              unsigned* __restrict__ part) {
    __shared__ int hist[NBUCK], runbase[NBUCK], cur[NBUCK];
    int tid = threadIdx.x;
    for (int i = tid; i < NBUCK; i += BLK) hist[i] = 0;
    __syncthreads();

    int e0 = blockIdx.x * EPB + tid * EPT;
    bool valid = (e0 + EPT <= NEDGE);  // NEDGE%4==0 -> all-or-nothing
    int c[EPT], r[EPT];
    if (valid) {
        *(int4*)&c[0] = *(const int4*)(col + e0);
        *(int4*)&r[0] = *(const int4*)(row + e0);
#pragma unroll
        for (int i = 0; i < EPT; ++i) atomicAdd(&hist[c[i] >> 6], 1);
    }
    __syncthreads();
    for (int i = tid; i < NBUCK; i += BLK) {
        runbase[i] = atomicAdd(&bcnt[i * BPAD], hist[i]);  // reserve run
        cur[i] = 0;
    }
    __syncthreads();
    if (valid) {
#pragma unroll
        for (int i = 0; i < EPT; ++i) {
            int q = c[i] >> 6;
            int pos = runbase[q] + atomicAdd(&cur[q], 1);
            part[q * BCAP + pos] = (unsigned)r[i] | ((unsigned)(c[i] & 63) << 16);
        }
    }
}

// ---------------- gemm: h = x @ W via bf16 MFMA (operand-swapped) ---------
// 8 waves x 16 nodes = 128 nodes per block; one 32KB fragment-ordered Bs
// fill per block (straight copy, conflict-free b128 reads).
__global__ __launch_bounds__(BLK) void k_gemm(const float* __restrict__ xsrc,
                                              const float* __restrict__ xtgt,
                                              const unsigned short* __restrict__ Wt,
                                              unsigned short* __restrict__ h,
                                              float* __restrict__ out) {
    __shared__ unsigned short Bs[DIM * DIM];  // 32 KB -> 4 blocks/CU

    const int tid = threadIdx.x;
    for (int idx = tid; idx < 2048; idx += BLK)
        ((uint4*)Bs)[idx] = ((const uint4*)Wt)[idx];

    const int wave = tid >> 6, lane = tid & 63;
    const int nl = lane & 15, quad = lane >> 4;

    // prefetch x fragments (issued before the Bs barrier)
    int node = blockIdx.x * 128 + wave * 16 + nl;
    int mc = (node < NTOT) ? node : (NTOT - 1);  // clamp tail loads
    const float* xrow = (mc < NSRC) ? (xsrc + (size_t)mc * DIM)
                                    : (xtgt + (size_t)(mc - NSRC) * DIM);
    float4 a[8];
#pragma unroll
    for (int s = 0; s < 4; ++s) {
        a[2 * s]     = *(const float4*)(xrow + s * 32 + quad * 8);
        a[2 * s + 1] = *(const float4*)(xrow + s * 32 + quad * 8 + 4);
    }
    __syncthreads();  // Bs ready

    float4v acc[8];
#pragma unroll
    for (int t = 0; t < 8; ++t) acc[t] = (float4v){0.f, 0.f, 0.f, 0.f};

#pragma unroll
    for (int s = 0; s < 4; ++s) {
        U8 af;
        af.u.x = pkbf(a[2 * s].x, a[2 * s].y);
        af.u.y = pkbf(a[2 * s].z, a[2 * s].w);
        af.u.z = pkbf(a[2 * s + 1].x, a[2 * s + 1].y);
        af.u.w = pkbf(a[2 * s + 1].z, a[2 * s + 1].w);
#pragma unroll
        for (int t = 0; t < 8; ++t) {
            short8 bf = *(const short8*)&Bs[((t * 4 + s) * 64 + lane) * 8];
            acc[t] = __builtin_amdgcn_mfma_f32_16x16x32_bf16(bf, af.s, acc[t], 0, 0, 0);
        }
    }

    if (node < NTOT) {
        unsigned short* hp = h + (size_t)node * DIM + quad * 4;
        float* op = out + (size_t)node * DIM + quad * 4;
        bool isrc = (node < NSRC);
#pragma unroll
        for (int t = 0; t < 8; ++t) {
            uint2 p;
            p.x = pkbf(acc[t][0], acc[t][1]);
            p.y = pkbf(acc[t][2], acc[t][3]);
            *(uint2*)(hp + t * 16) = p;
            if (isrc) {  // source nodes: deg=1 -> out = relu(h), fp32 acc
                float4 o;
                o.x = fmaxf(acc[t][0], 0.f);
                o.y = fmaxf(acc[t][1], 0.f);
                o.z = fmaxf(acc[t][2], 0.f);
                o.w = fmaxf(acc[t][3], 0.f);
                *(float4*)(op + t * 16) = o;
            }
        }
    }
}

// ---------------- k_back v2: chunk-sorted register gather-reduce ----------
// sort bucket edges by key = (src_chunk(2b) << 6) | c_local(6b); reduce
// iterates chunk-major with persistent acc[8 targets][8] registers.
// - segments are tiny (~4 edges) -> mostly straight-line, loads from
//   independent segments pipeline (high MLP)
// - all blocks sweep h's source range chunk-by-chunk -> L2-friendly fills
__global__ __launch_bounds__(BLK) void k_back(const int* __restrict__ bcnt,
                                              const unsigned* __restrict__ part,
                                              const unsigned short* __restrict__ h,
                                              float* __restrict__ out) {
    __shared__ unsigned short srt[BCAP];  // 3 KB: source rows, (chunk,c) order
    __shared__ int hist[256], st[256], cur[256], bufA[256], bufB[256];
    __shared__ int degs[64];

    int q = blockIdx.x, tid = threadIdx.x;
    int n = bcnt[q * BPAD];
    int base = q * BCAP;

    if (tid < 256) hist[tid] = 0;
    __syncthreads();
    // pass 1: histogram by key (re-read part in pass 2; it's L2-hot)
    for (int i = tid; i < n; i += BLK) {
        unsigned p = part[base + i];
        int key = (((p >> 14) & 3) << 6) | (p >> 16);  // chunk = row>>14
        atomicAdd(&hist[key], 1);
    }
    __syncthreads();
    if (tid < 64)
        degs[tid] = hist[tid] + hist[tid + 64] + hist[tid + 128] + hist[tid + 192];
    // exclusive scan of hist[256]
    if (tid < 256) bufA[tid] = hist[tid];
    int* src = bufA; int* dst = bufB;
    for (int d = 1; d < 256; d <<= 1) {
        __syncthreads();
        if (tid < 256) dst[tid] = src[tid] + ((tid >= d) ? src[tid - d] : 0);
        int* tp = src; src = dst; dst = tp;
    }
    __syncthreads();
    if (tid < 256) { int e = src[tid] - hist[tid]; st[tid] = e; cur[tid] = e; }
    __syncthreads();
    // pass 2: scatter source rows
    for (int i = tid; i < n; i += BLK) {
        unsigned p = part[base + i];
        int key = (((p >> 14) & 3) << 6) | (p >> 16);
        int pos = atomicAdd(&cur[key], 1);
        srt[pos] = (unsigned short)(p & 0xffffu);
    }
    __syncthreads();

    // ---------------- reduce ----------------
    int w = tid >> 6, lane = tid & 63;
    int qd = lane >> 4, ql = lane & 15;  // quad owns one edge; 16 lanes x 16B
    int cl0 = w * 8;                     // wave's first local target

    float acc[8][8];
#pragma unroll
    for (int t = 0; t < 8; ++t)
#pragma unroll
        for (int j = 0; j < 8; ++j) acc[t][j] = 0.f;

#pragma unroll
    for (int p = 0; p < 4; ++p) {
#pragma unroll
        for (int t = 0; t < 8; ++t) {
            int seg = (p << 6) | (cl0 + t);
            int ns = hist[seg], s0 = st[seg];
            int kk = 0;
            for (; kk + 4 <= ns; kk += 4) {
                int r = (int)srt[s0 + kk + qd];
                uint4 d = *(const uint4*)(h + (size_t)r * DIM + ql * 8);
                acc[t][0] += bf2f(d.x & 0xffff); acc[t][1] += bf2f(d.x >> 16);
                acc[t][2] += bf2f(d.y & 0xffff); acc[t][3] += bf2f(d.y >> 16);
                acc[t][4] += bf2f(d.z & 0xffff); acc[t][5] += bf2f(d.z >> 16);
                acc[t][6] += bf2f(d.w & 0xffff); acc[t][7] += bf2f(d.w >> 16);
            }
            if (qd < ns - kk) {  // remainder 0..3
                int r = (int)srt[s0 + kk + qd];
                uint4 d = *(const uint4*)(h + (size_t)r * DIM + ql * 8);
                acc[t][0] += bf2f(d.x & 0xffff); acc[t][1] += bf2f(d.x >> 16);
                acc[t][2] += bf2f(d.y & 0xffff); acc[t][3] += bf2f(d.y >> 16);
                acc[t][4] += bf2f(d.z & 0xffff); acc[t][5] += bf2f(d.z >> 16);
                acc[t][6] += bf2f(d.w & 0xffff); acc[t][7] += bf2f(d.w >> 16);
            }
        }
    }

#pragma unroll
    for (int t = 0; t < 8; ++t) {
        // combine quarters: butterfly over lane bits 4,5 (all lanes exec)
#pragma unroll
        for (int j = 0; j < 8; ++j) {
            acc[t][j] += __shfl_xor(acc[t][j], 16, 64);
            acc[t][j] += __shfl_xor(acc[t][j], 32, 64);
        }
        int c = q * 64 + cl0 + t;
        if (qd == 0 && c < NTGT) {
            int nn = degs[cl0 + t];
            float di = rsqrtf(1.0f + (float)nn);
            float dd = di * di;
            uint4 dh = *(const uint4*)(h + (size_t)(NSRC + c) * DIM + ql * 8);
            float4 o0, o1;
            o0.x = fmaxf(di * acc[t][0] + dd * bf2f(dh.x & 0xffff), 0.f);
            o0.y = fmaxf(di * acc[t][1] + dd * bf2f(dh.x >> 16), 0.f);
            o0.z = fmaxf(di * acc[t][2] + dd * bf2f(dh.y & 0xffff), 0.f);
            o0.w = fmaxf(di * acc[t][3] + dd * bf2f(dh.y >> 16), 0.f);
            o1.x = fmaxf(di * acc[t][4] + dd * bf2f(dh.z & 0xffff), 0.f);
            o1.y = fmaxf(di * acc[t][5] + dd * bf2f(dh.z >> 16), 0.f);
            o1.z = fmaxf(di * acc[t][6] + dd * bf2f(dh.w & 0xffff), 0.f);
            o1.w = fmaxf(di * acc[t][7] + dd * bf2f(dh.w >> 16), 0.f);
            float* op = out + (size_t)(NSRC + c) * DIM + ql * 8;
            *(float4*)op = o0;
            *(float4*)(op + 4) = o1;
        }
    }
}

extern "C" void kernel_launch(void* const* d_in, const int* in_sizes, int n_in,
                              void* d_out, int out_size, void* d_ws, size_t ws_size,
                              hipStream_t stream) {
    const int* ei     = (const int*)d_in[0];    // [2, E] int32
    const float* xsrc = (const float*)d_in[1];  // [NSRC, 128]
    const float* xtgt = (const float*)d_in[2];  // [NTGT, 128]
    const float* W    = (const float*)d_in[3];  // [128, 128]
    float* out = (float*)d_out;                 // [NTOT, 128]

    const int* row = ei;
    const int* col = ei + NEDGE;

    char* ws = (char*)d_ws;
    unsigned short* h  = (unsigned short*)ws;  ws += (size_t)NTOT * DIM * 2;   // 25.6 MB
    unsigned short* Wt = (unsigned short*)ws;  ws += DIM * DIM * 2;            // 32 KB
    unsigned* part = (unsigned*)ws;            ws += (size_t)NBUCK * BCAP * 4; // 4.8 MB
    int* bcnt = (int*)ws;                      ws += NBUCK * BPAD * 4;         // 50 KB

    k_prep<<<64, 256, 0, stream>>>(W, Wt, bcnt);
    k_part<<<PBLK, BLK, 0, stream>>>(row, col, bcnt, part);
    k_gemm<<<GEMM_GRID, BLK, 0, stream>>>(xsrc, xtgt, Wt, h, out);
    k_back<<<NBUCK, BLK, 0, stream>>>(bcnt, part, h, out);
}

// Round 6
// 185.718 us; speedup vs baseline: 1.0607x; 1.0607x over previous
//
#include <hip/hip_runtime.h>
#include <hip/hip_bf16.h>
#include <math.h>

#define NSRC 50000
#define NTGT 50000
#define NTOT 100000
#define NEDGE 800000
#define DIM 128

#define NBUCK 1563      // buckets of 32 targets (49999>>5 = 1562)
#define BCAP 768        // max edges/bucket (mean 512, sigma 22.6 -> +11 sigma)
#define BPAD 16         // bcnt stride (ints): one 64B line per bucket counter
#define BLK 512         // 8 waves per block
#define EPT 4           // edges per thread in partition (512*4 = 2048)
#define EPB 2048        // edges per partition block
#define PBLK 391        // ceil(800000 / 2048)
#define GEMM_GRID 782   // ceil(100000 / 128) : 128 nodes per gemm block

typedef __attribute__((ext_vector_type(8))) short short8;
typedef __attribute__((ext_vector_type(4))) float float4v;

union U8 { short8 s; uint4 u; };

__device__ __forceinline__ unsigned short f2bf(float f) {
    unsigned u = __float_as_uint(f);
    unsigned r = (u + 0x7FFFu + ((u >> 16) & 1u)) >> 16;  // RNE
    return (unsigned short)r;
}
__device__ __forceinline__ float bf2f(unsigned us) {
    return __uint_as_float(us << 16);
}
// packed RNE f32x2 -> bf16x2 (v_cvt_pk_bf16_f32)
__device__ __forceinline__ unsigned pkbf(float lo, float hi) {
    __hip_bfloat162 b = __float22bfloat162_rn(make_float2(lo, hi));
    return *(unsigned*)&b;
}

// ---------------- prep: W -> Wt (bf16, MFMA-fragment order) + zero bcnt ---
// Wt linear idx = ((t*4+s)*64 + lane)*8 + j  ->  W[(s*32+qd*8+j)][t*16+nl]
__global__ __launch_bounds__(256) void k_prep(const float* __restrict__ W,
                                              unsigned short* __restrict__ Wt,
                                              int* __restrict__ bcnt) {
    int i = blockIdx.x * 256 + threadIdx.x;  // grid = 98 blocks -> i < 25088
    if (i < NBUCK * BPAD) bcnt[i] = 0;
    if (i < DIM * DIM) {
        int j = i & 7, lane = (i >> 3) & 63, ts = i >> 9;
        int t = ts >> 2, s = ts & 3;
        int nl = lane & 15, qd = lane >> 4;
        Wt[i] = f2bf(W[(s * 32 + qd * 8 + j) * DIM + (t * 16 + nl)]);
    }
}

// ---------------- partition: edges -> 32-target buckets -------------------
// packed entry: row (16b) | c_local (5b in bits 16..20)
__global__ __launch_bounds__(BLK) void k_part(const int* __restrict__ row,
                                              const int* __restrict__ col,
                                              int* __restrict__ bcnt,
                                              unsigned* __restrict__ part) {
    __shared__ int hist[NBUCK], runbase[NBUCK], cur[NBUCK];  // 18.8 KB
    int tid = threadIdx.x;
    for (int i = tid; i < NBUCK; i += BLK) hist[i] = 0;
    __syncthreads();

    int e0 = blockIdx.x * EPB + tid * EPT;
    bool valid = (e0 + EPT <= NEDGE);  // NEDGE%4==0 -> all-or-nothing
    int c[EPT], r[EPT];
    if (valid) {
        *(int4*)&c[0] = *(const int4*)(col + e0);
        *(int4*)&r[0] = *(const int4*)(row + e0);
#pragma unroll
        for (int i = 0; i < EPT; ++i) atomicAdd(&hist[c[i] >> 5], 1);
    }
    __syncthreads();
    for (int i = tid; i < NBUCK; i += BLK) {
        runbase[i] = atomicAdd(&bcnt[i * BPAD], hist[i]);  // reserve run
        cur[i] = 0;
    }
    __syncthreads();
    if (valid) {
#pragma unroll
        for (int i = 0; i < EPT; ++i) {
            int q = c[i] >> 5;
            int pos = runbase[q] + atomicAdd(&cur[q], 1);
            part[q * BCAP + pos] = (unsigned)r[i] | ((unsigned)(c[i] & 31) << 16);
        }
    }
}

// ---------------- gemm: h = x @ W via bf16 MFMA (operand-swapped) ---------
// 8 waves x 16 nodes = 128 nodes per block; one 32KB fragment-ordered Bs
// fill per block (straight copy, conflict-free b128 reads).
__global__ __launch_bounds__(BLK) void k_gemm(const float* __restrict__ xsrc,
                                              const float* __restrict__ xtgt,
                                              const unsigned short* __restrict__ Wt,
                                              unsigned short* __restrict__ h,
                                              float* __restrict__ out) {
    __shared__ unsigned short Bs[DIM * DIM];  // 32 KB -> 4 blocks/CU

    const int tid = threadIdx.x;
    for (int idx = tid; idx < 2048; idx += BLK)
        ((uint4*)Bs)[idx] = ((const uint4*)Wt)[idx];

    const int wave = tid >> 6, lane = tid & 63;
    const int nl = lane & 15, quad = lane >> 4;

    // prefetch x fragments (issued before the Bs barrier)
    int node = blockIdx.x * 128 + wave * 16 + nl;
    int mc = (node < NTOT) ? node : (NTOT - 1);  // clamp tail loads
    const float* xrow = (mc < NSRC) ? (xsrc + (size_t)mc * DIM)
                                    : (xtgt + (size_t)(mc - NSRC) * DIM);
    float4 a[8];
#pragma unroll
    for (int s = 0; s < 4; ++s) {
        a[2 * s]     = *(const float4*)(xrow + s * 32 + quad * 8);
        a[2 * s + 1] = *(const float4*)(xrow + s * 32 + quad * 8 + 4);
    }
    __syncthreads();  // Bs ready

    float4v acc[8];
#pragma unroll
    for (int t = 0; t < 8; ++t) acc[t] = (float4v){0.f, 0.f, 0.f, 0.f};

#pragma unroll
    for (int s = 0; s < 4; ++s) {
        U8 af;
        af.u.x = pkbf(a[2 * s].x, a[2 * s].y);
        af.u.y = pkbf(a[2 * s].z, a[2 * s].w);
        af.u.z = pkbf(a[2 * s + 1].x, a[2 * s + 1].y);
        af.u.w = pkbf(a[2 * s + 1].z, a[2 * s + 1].w);
#pragma unroll
        for (int t = 0; t < 8; ++t) {
            short8 bf = *(const short8*)&Bs[((t * 4 + s) * 64 + lane) * 8];
            acc[t] = __builtin_amdgcn_mfma_f32_16x16x32_bf16(bf, af.s, acc[t], 0, 0, 0);
        }
    }

    if (node < NTOT) {
        unsigned short* hp = h + (size_t)node * DIM + quad * 4;
        float* op = out + (size_t)node * DIM + quad * 4;
        bool isrc = (node < NSRC);
#pragma unroll
        for (int t = 0; t < 8; ++t) {
            uint2 p;
            p.x = pkbf(acc[t][0], acc[t][1]);
            p.y = pkbf(acc[t][2], acc[t][3]);
            *(uint2*)(hp + t * 16) = p;
            if (isrc) {  // source nodes: deg=1 -> out = relu(h), fp32 acc
                float4 o;
                o.x = fmaxf(acc[t][0], 0.f);
                o.y = fmaxf(acc[t][1], 0.f);
                o.z = fmaxf(acc[t][2], 0.f);
                o.w = fmaxf(acc[t][3], 0.f);
                *(float4*)(op + t * 16) = o;
            }
        }
    }
}

// ---------------- per-bucket sort (LDS) + paired-target gather-reduce -----
// 32-target buckets, 512 thr: wave w owns targets w*4..w*4+3, processed as
// 2 pairs with named accA/accB register accumulators (static indexing only)
// -> ~8 independent gather loads in flight per lane. Quarter-wave per edge.
__global__ __launch_bounds__(BLK) void k_back(const int* __restrict__ bcnt,
                                              const unsigned* __restrict__ part,
                                              const unsigned short* __restrict__ h,
                                              float* __restrict__ out) {
    __shared__ unsigned ebuf[BCAP];       // 3 KB
    __shared__ unsigned short srt[BCAP];  // 1.5 KB
    __shared__ int hist[32], st[32], cur[32], bufA[32], bufB[32];

    int q = blockIdx.x, tid = threadIdx.x;
    int n = bcnt[q * BPAD];
    int base = q * BCAP;

    if (tid < 32) hist[tid] = 0;
    __syncthreads();
    for (int i = tid; i < n; i += BLK) {
        unsigned p = part[base + i];
        ebuf[i] = p;
        atomicAdd(&hist[p >> 16], 1);
    }
    __syncthreads();

    // exclusive scan of hist[32] (first 32 threads, double-buffered)
    if (tid < 32) bufA[tid] = hist[tid];
    int* src = bufA; int* dst = bufB;
    for (int d = 1; d < 32; d <<= 1) {
        __syncthreads();
        if (tid < 32) dst[tid] = src[tid] + ((tid >= d) ? src[tid - d] : 0);
        int* tp = src; src = dst; dst = tp;
    }
    __syncthreads();
    if (tid < 32) { int e = src[tid] - hist[tid]; st[tid] = e; cur[tid] = e; }
    __syncthreads();
    for (int i = tid; i < n; i += BLK) {
        unsigned p = ebuf[i];
        int pos = atomicAdd(&cur[p >> 16], 1);
        srt[pos] = (unsigned short)(p & 0xffffu);
    }
    __syncthreads();

    // ---------------- reduce: 2 target-pairs per wave ----------------
    int w = tid >> 6, lane = tid & 63;
    int qd = lane >> 4, ql = lane & 15;  // quad owns one edge; 16 lanes x 16B
    int cl0 = w * 4;                     // wave's first local target

    for (int pr = 0; pr < 2; ++pr) {
        int ca = cl0 + pr * 2, cb = ca + 1;
        int nA = hist[ca], sA = st[ca];
        int nB = hist[cb], sB = st[cb];

        float accA[8], accB[8];
#pragma unroll
        for (int i = 0; i < 8; ++i) { accA[i] = 0.f; accB[i] = 0.f; }

        int itA = (nA + 3) >> 2, itB = (nB + 3) >> 2;
        int itn = (itA > itB) ? itA : itB;
        for (int k = 0; k < itn; ++k) {
            int e = 4 * k + qd;
            if (e < nA) {
                int r = (int)srt[sA + e];
                uint4 d = *(const uint4*)(h + (size_t)r * DIM + ql * 8);
                accA[0] += bf2f(d.x & 0xffff); accA[1] += bf2f(d.x >> 16);
                accA[2] += bf2f(d.y & 0xffff); accA[3] += bf2f(d.y >> 16);
                accA[4] += bf2f(d.z & 0xffff); accA[5] += bf2f(d.z >> 16);
                accA[6] += bf2f(d.w & 0xffff); accA[7] += bf2f(d.w >> 16);
            }
            if (e < nB) {
                int r = (int)srt[sB + e];
                uint4 d = *(const uint4*)(h + (size_t)r * DIM + ql * 8);
                accB[0] += bf2f(d.x & 0xffff); accB[1] += bf2f(d.x >> 16);
                accB[2] += bf2f(d.y & 0xffff); accB[3] += bf2f(d.y >> 16);
                accB[4] += bf2f(d.z & 0xffff); accB[5] += bf2f(d.z >> 16);
                accB[6] += bf2f(d.w & 0xffff); accB[7] += bf2f(d.w >> 16);
            }
        }

        // combine quarters: butterfly over lane bits 4,5 (all lanes exec)
#pragma unroll
        for (int i = 0; i < 8; ++i) {
            accA[i] += __shfl_xor(accA[i], 16, 64);
            accA[i] += __shfl_xor(accA[i], 32, 64);
            accB[i] += __shfl_xor(accB[i], 16, 64);
            accB[i] += __shfl_xor(accB[i], 32, 64);
        }

        int c0 = q * 32 + ca;
        if (qd == 0 && c0 < NTGT) {
            float di = rsqrtf(1.0f + (float)nA);
            float dd = di * di;
            uint4 dh = *(const uint4*)(h + (size_t)(NSRC + c0) * DIM + ql * 8);
            float4 o0, o1;
            o0.x = fmaxf(di * accA[0] + dd * bf2f(dh.x & 0xffff), 0.f);
            o0.y = fmaxf(di * accA[1] + dd * bf2f(dh.x >> 16), 0.f);
            o0.z = fmaxf(di * accA[2] + dd * bf2f(dh.y & 0xffff), 0.f);
            o0.w = fmaxf(di * accA[3] + dd * bf2f(dh.y >> 16), 0.f);
            o1.x = fmaxf(di * accA[4] + dd * bf2f(dh.z & 0xffff), 0.f);
            o1.y = fmaxf(di * accA[5] + dd * bf2f(dh.z >> 16), 0.f);
            o1.z = fmaxf(di * accA[6] + dd * bf2f(dh.w & 0xffff), 0.f);
            o1.w = fmaxf(di * accA[7] + dd * bf2f(dh.w >> 16), 0.f);
            float* op = out + (size_t)(NSRC + c0) * DIM + ql * 8;
            *(float4*)op = o0;
            *(float4*)(op + 4) = o1;
        }
        int c1 = q * 32 + cb;
        if (qd == 0 && c1 < NTGT) {
            float di = rsqrtf(1.0f + (float)nB);
            float dd = di * di;
            uint4 dh = *(const uint4*)(h + (size_t)(NSRC + c1) * DIM + ql * 8);
            float4 o0, o1;
            o0.x = fmaxf(di * accB[0] + dd * bf2f(dh.x & 0xffff), 0.f);
            o0.y = fmaxf(di * accB[1] + dd * bf2f(dh.x >> 16), 0.f);
            o0.z = fmaxf(di * accB[2] + dd * bf2f(dh.y & 0xffff), 0.f);
            o0.w = fmaxf(di * accB[3] + dd * bf2f(dh.y >> 16), 0.f);
            o1.x = fmaxf(di * accB[4] + dd * bf2f(dh.z & 0xffff), 0.f);
            o1.y = fmaxf(di * accB[5] + dd * bf2f(dh.z >> 16), 0.f);
            o1.z = fmaxf(di * accB[6] + dd * bf2f(dh.w & 0xffff), 0.f);
            o1.w = fmaxf(di * accB[7] + dd * bf2f(dh.w >> 16), 0.f);
            float* op = out + (size_t)(NSRC + c1) * DIM + ql * 8;
            *(float4*)op = o0;
            *(float4*)(op + 4) = o1;
        }
    }
}

extern "C" void kernel_launch(void* const* d_in, const int* in_sizes, int n_in,
                              void* d_out, int out_size, void* d_ws, size_t ws_size,
                              hipStream_t stream) {
    const int* ei     = (const int*)d_in[0];    // [2, E] int32
    const float* xsrc = (const float*)d_in[1];  // [NSRC, 128]
    const float* xtgt = (const float*)d_in[2];  // [NTGT, 128]
    const float* W    = (const float*)d_in[3];  // [128, 128]
    float* out = (float*)d_out;                 // [NTOT, 128]

    const int* row = ei;
    const int* col = ei + NEDGE;

    char* ws = (char*)d_ws;
    unsigned short* h  = (unsigned short*)ws;  ws += (size_t)NTOT * DIM * 2;   // 25.6 MB
    unsigned short* Wt = (unsigned short*)ws;  ws += DIM * DIM * 2;            // 32 KB
    unsigned* part = (unsigned*)ws;            ws += (size_t)NBUCK * BCAP * 4; // 4.8 MB
    int* bcnt = (int*)ws;                      ws += NBUCK * BPAD * 4;         // 100 KB

    k_prep<<<98, 256, 0, stream>>>(W, Wt, bcnt);
    k_part<<<PBLK, BLK, 0, stream>>>(row, col, bcnt, part);
    k_gemm<<<GEMM_GRID, BLK, 0, stream>>>(xsrc, xtgt, Wt, h, out);
    k_back<<<NBUCK, BLK, 0, stream>>>(bcnt, part, h, out);
}

// Round 7
// 164.644 us; speedup vs baseline: 1.1965x; 1.1280x over previous
//
#include <hip/hip_runtime.h>
#include <hip/hip_bf16.h>
#include <math.h>

#define NSRC 50000
#define NTGT 50000
#define NTOT 100000
#define NEDGE 800000
#define DIM 128

#define NBUCK 782       // buckets of 64 targets (49999>>6 = 781)
#define BCAP 1536       // max edges/bucket (mean 1024, sigma 32 -> +16 sigma)
#define BPAD 16         // bcnt stride (ints): one 64B line per bucket counter
#define BLK 512         // 8 waves per block
#define EPT 4           // edges per thread in partition path (512*4 = 2048)
#define EPB2 2048       // edges per partition block
#define PBLK2 391       // ceil(800000 / 2048)
#define GEMM_GRID 782   // ceil(100000 / 128) : 128 nodes per gemm block
#define FGRID 1173      // 391 partition (bid%3==0) + 782 gemm

typedef __attribute__((ext_vector_type(8))) short short8;
typedef __attribute__((ext_vector_type(4))) float float4v;

union U8 { short8 s; uint4 u; };

__device__ __forceinline__ unsigned short f2bf(float f) {
    unsigned u = __float_as_uint(f);
    unsigned r = (u + 0x7FFFu + ((u >> 16) & 1u)) >> 16;  // RNE
    return (unsigned short)r;
}
__device__ __forceinline__ float bf2f(unsigned us) {
    return __uint_as_float(us << 16);
}
// packed RNE f32x2 -> bf16x2 (v_cvt_pk_bf16_f32)
__device__ __forceinline__ unsigned pkbf(float lo, float hi) {
    __hip_bfloat162 b = __float22bfloat162_rn(make_float2(lo, hi));
    return *(unsigned*)&b;
}

// ---------------- prep: W -> Wt (bf16, MFMA-fragment order) + zero bcnt ---
// Wt linear idx = ((t*4+s)*64 + lane)*8 + j  ->  W[(s*32+qd*8+j)][t*16+nl]
__global__ __launch_bounds__(256) void k_prep(const float* __restrict__ W,
                                              unsigned short* __restrict__ Wt,
                                              int* __restrict__ bcnt) {
    int i = blockIdx.x * 256 + threadIdx.x;  // grid = 64 blocks -> i < 16384
    if (i < NBUCK * BPAD) bcnt[i] = 0;
    int j = i & 7, lane = (i >> 3) & 63, ts = i >> 9;
    int t = ts >> 2, s = ts & 3;
    int nl = lane & 15, qd = lane >> 4;
    Wt[i] = f2bf(W[(s * 32 + qd * 8 + j) * DIM + (t * 16 + nl)]);
}

// ---------------- fused: edge partition (every 3rd block) + GEMM ----------
// 512 threads: partition path = 2048 edges (EPT 4); gemm path = 8 waves x
// 16 nodes = 128 nodes per block, one 32KB Bs fill per 128 nodes.
__global__ __launch_bounds__(BLK) void k_front(const int* __restrict__ row,
                                               const int* __restrict__ col,
                                               int* __restrict__ bcnt,
                                               unsigned* __restrict__ part,
                                               const float* __restrict__ xsrc,
                                               const float* __restrict__ xtgt,
                                               const unsigned short* __restrict__ Wt,
                                               unsigned short* __restrict__ h,
                                               float* __restrict__ out) {
    __shared__ union SM {
        struct { int hist[NBUCK]; int runbase[NBUCK]; int cur[NBUCK]; } p;
        unsigned short Bs[DIM * DIM];  // 32 KB -> 4 blocks/CU, 32 waves/CU
    } sm;

    const int tid = threadIdx.x;
    const int bid = blockIdx.x;

    if (bid % 3 == 0) {
        // ---------------- partition path ----------------
        for (int i = tid; i < NBUCK; i += BLK) sm.p.hist[i] = 0;
        __syncthreads();

        int e0 = (bid / 3) * EPB2 + tid * EPT;
        bool valid = (e0 + EPT <= NEDGE);  // NEDGE%4==0 -> all-or-nothing
        int c[EPT], r[EPT];
        if (valid) {
            *(int4*)&c[0] = *(const int4*)(col + e0);
            *(int4*)&r[0] = *(const int4*)(row + e0);
#pragma unroll
            for (int i = 0; i < EPT; ++i) atomicAdd(&sm.p.hist[c[i] >> 6], 1);
        }
        __syncthreads();
        for (int i = tid; i < NBUCK; i += BLK) {
            sm.p.runbase[i] = atomicAdd(&bcnt[i * BPAD], sm.p.hist[i]);  // reserve run
            sm.p.cur[i] = 0;
        }
        __syncthreads();
        if (valid) {
#pragma unroll
            for (int i = 0; i < EPT; ++i) {
                int q = c[i] >> 6;
                int pos = sm.p.runbase[q] + atomicAdd(&sm.p.cur[q], 1);
                part[q * BCAP + pos] = (unsigned)r[i] | ((unsigned)(c[i] & 63) << 16);
            }
        }
        return;
    }

    // ---------------- gemm path ----------------
    const int gb = bid - bid / 3 - 1;  // 0..GEMM_GRID-1

    // Wt is already fragment-ordered: straight 32 KB copy, conflict-free
    for (int idx = tid; idx < 2048; idx += BLK)
        ((uint4*)sm.Bs)[idx] = ((const uint4*)Wt)[idx];

    const int wave = tid >> 6, lane = tid & 63;
    const int nl = lane & 15, quad = lane >> 4;

    // prefetch x fragments (issued before the Bs barrier)
    int node = gb * 128 + wave * 16 + nl;
    int mc = (node < NTOT) ? node : (NTOT - 1);  // clamp tail loads
    const float* xrow = (mc < NSRC) ? (xsrc + (size_t)mc * DIM)
                                    : (xtgt + (size_t)(mc - NSRC) * DIM);
    float4 a[8];
#pragma unroll
    for (int s = 0; s < 4; ++s) {
        a[2 * s]     = *(const float4*)(xrow + s * 32 + quad * 8);
        a[2 * s + 1] = *(const float4*)(xrow + s * 32 + quad * 8 + 4);
    }
    __syncthreads();  // Bs ready

    float4v acc[8];
#pragma unroll
    for (int t = 0; t < 8; ++t) acc[t] = (float4v){0.f, 0.f, 0.f, 0.f};

#pragma unroll
    for (int s = 0; s < 4; ++s) {
        U8 af;
        af.u.x = pkbf(a[2 * s].x, a[2 * s].y);
        af.u.y = pkbf(a[2 * s].z, a[2 * s].w);
        af.u.z = pkbf(a[2 * s + 1].x, a[2 * s + 1].y);
        af.u.w = pkbf(a[2 * s + 1].z, a[2 * s + 1].w);
#pragma unroll
        for (int t = 0; t < 8; ++t) {
            short8 bf = *(const short8*)&sm.Bs[((t * 4 + s) * 64 + lane) * 8];
            acc[t] = __builtin_amdgcn_mfma_f32_16x16x32_bf16(bf, af.s, acc[t], 0, 0, 0);
        }
    }

    if (node < NTOT) {
        unsigned short* hp = h + (size_t)node * DIM + quad * 4;
        float* op = out + (size_t)node * DIM + quad * 4;
        bool isrc = (node < NSRC);
#pragma unroll
        for (int t = 0; t < 8; ++t) {
            uint2 p;
            p.x = pkbf(acc[t][0], acc[t][1]);
            p.y = pkbf(acc[t][2], acc[t][3]);
            *(uint2*)(hp + t * 16) = p;
            if (isrc) {  // source nodes: deg=1 -> out = relu(h), fp32 acc
                float4 o;
                o.x = fmaxf(acc[t][0], 0.f);
                o.y = fmaxf(acc[t][1], 0.f);
                o.z = fmaxf(acc[t][2], 0.f);
                o.w = fmaxf(acc[t][3], 0.f);
                *(float4*)(op + t * 16) = o;
            }
        }
    }
}

// ---------------- per-bucket sort (LDS) + paired-target gather-reduce -----
// 64-target buckets, 512 thr: wave w owns targets w*8..w*8+7, processed as
// 4 pairs with named accA/accB register accumulators (static indexing only)
// -> ~8 independent gather loads in flight per lane. Quarter-wave per edge.
// Per-target edge order identical to serial version (edge 4k+qd per quad).
__global__ __launch_bounds__(BLK) void k_back(const int* __restrict__ bcnt,
                                              const unsigned* __restrict__ part,
                                              const unsigned short* __restrict__ h,
                                              float* __restrict__ out) {
    __shared__ unsigned ebuf[BCAP];       // 6 KB
    __shared__ unsigned short srt[BCAP];  // 3 KB
    __shared__ int hist[64], bufA[64], bufB[64], cur[64], st[64];

    int q = blockIdx.x, tid = threadIdx.x;
    int n = bcnt[q * BPAD];
    int base = q * BCAP;

    if (tid < 64) hist[tid] = 0;
    __syncthreads();
    for (int i = tid; i < n; i += BLK) {
        unsigned p = part[base + i];
        ebuf[i] = p;
        atomicAdd(&hist[p >> 16], 1);
    }
    __syncthreads();

    // exclusive scan of hist[64] (first 64 threads, double-buffered)
    if (tid < 64) bufA[tid] = hist[tid];
    int* src = bufA; int* dst = bufB;
    for (int d = 1; d < 64; d <<= 1) {
        __syncthreads();
        if (tid < 64) dst[tid] = src[tid] + ((tid >= d) ? src[tid - d] : 0);
        int* tp = src; src = dst; dst = tp;
    }
    __syncthreads();
    if (tid < 64) {
        int excl = src[tid] - hist[tid];
        cur[tid] = excl;
        st[tid] = excl;
    }
    __syncthreads();
    for (int i = tid; i < n; i += BLK) {
        unsigned p = ebuf[i];
        int pos = atomicAdd(&cur[p >> 16], 1);
        srt[pos] = (unsigned short)(p & 0xffffu);
    }
    __syncthreads();

    // ---------------- reduce: 4 target-pairs per wave ----------------
    int w = tid >> 6, lane = tid & 63;
    int qd = lane >> 4, ql = lane & 15;  // quad owns one edge; 16 lanes x 16B
    int cl0 = w * 8;                     // wave's first local target

    for (int pr = 0; pr < 4; ++pr) {
        int ca = cl0 + pr * 2, cb = ca + 1;
        int nA = hist[ca], sA = st[ca];
        int nB = hist[cb], sB = st[cb];

        float accA[8], accB[8];
#pragma unroll
        for (int i = 0; i < 8; ++i) { accA[i] = 0.f; accB[i] = 0.f; }

        int itA = (nA + 3) >> 2, itB = (nB + 3) >> 2;
        int itn = (itA > itB) ? itA : itB;
        for (int k = 0; k < itn; ++k) {
            int e = 4 * k + qd;
            if (e < nA) {
                int r = (int)srt[sA + e];
                uint4 d = *(const uint4*)(h + (size_t)r * DIM + ql * 8);
                accA[0] += bf2f(d.x & 0xffff); accA[1] += bf2f(d.x >> 16);
                accA[2] += bf2f(d.y & 0xffff); accA[3] += bf2f(d.y >> 16);
                accA[4] += bf2f(d.z & 0xffff); accA[5] += bf2f(d.z >> 16);
                accA[6] += bf2f(d.w & 0xffff); accA[7] += bf2f(d.w >> 16);
            }
            if (e < nB) {
                int r = (int)srt[sB + e];
                uint4 d = *(const uint4*)(h + (size_t)r * DIM + ql * 8);
                accB[0] += bf2f(d.x & 0xffff); accB[1] += bf2f(d.x >> 16);
                accB[2] += bf2f(d.y & 0xffff); accB[3] += bf2f(d.y >> 16);
                accB[4] += bf2f(d.z & 0xffff); accB[5] += bf2f(d.z >> 16);
                accB[6] += bf2f(d.w & 0xffff); accB[7] += bf2f(d.w >> 16);
            }
        }

        // combine quarters: butterfly over lane bits 4,5 (all lanes exec)
#pragma unroll
        for (int i = 0; i < 8; ++i) {
            accA[i] += __shfl_xor(accA[i], 16, 64);
            accA[i] += __shfl_xor(accA[i], 32, 64);
            accB[i] += __shfl_xor(accB[i], 16, 64);
            accB[i] += __shfl_xor(accB[i], 32, 64);
        }

        int c0 = q * 64 + ca;
        if (qd == 0 && c0 < NTGT) {
            float di = rsqrtf(1.0f + (float)nA);
            float dd = di * di;
            uint4 dh = *(const uint4*)(h + (size_t)(NSRC + c0) * DIM + ql * 8);
            float4 o0, o1;
            o0.x = fmaxf(di * accA[0] + dd * bf2f(dh.x & 0xffff), 0.f);
            o0.y = fmaxf(di * accA[1] + dd * bf2f(dh.x >> 16), 0.f);
            o0.z = fmaxf(di * accA[2] + dd * bf2f(dh.y & 0xffff), 0.f);
            o0.w = fmaxf(di * accA[3] + dd * bf2f(dh.y >> 16), 0.f);
            o1.x = fmaxf(di * accA[4] + dd * bf2f(dh.z & 0xffff), 0.f);
            o1.y = fmaxf(di * accA[5] + dd * bf2f(dh.z >> 16), 0.f);
            o1.z = fmaxf(di * accA[6] + dd * bf2f(dh.w & 0xffff), 0.f);
            o1.w = fmaxf(di * accA[7] + dd * bf2f(dh.w >> 16), 0.f);
            float* op = out + (size_t)(NSRC + c0) * DIM + ql * 8;
            *(float4*)op = o0;
            *(float4*)(op + 4) = o1;
        }
        int c1 = q * 64 + cb;
        if (qd == 0 && c1 < NTGT) {
            float di = rsqrtf(1.0f + (float)nB);
            float dd = di * di;
            uint4 dh = *(const uint4*)(h + (size_t)(NSRC + c1) * DIM + ql * 8);
            float4 o0, o1;
            o0.x = fmaxf(di * accB[0] + dd * bf2f(dh.x & 0xffff), 0.f);
            o0.y = fmaxf(di * accB[1] + dd * bf2f(dh.x >> 16), 0.f);
            o0.z = fmaxf(di * accB[2] + dd * bf2f(dh.y & 0xffff), 0.f);
            o0.w = fmaxf(di * accB[3] + dd * bf2f(dh.y >> 16), 0.f);
            o1.x = fmaxf(di * accB[4] + dd * bf2f(dh.z & 0xffff), 0.f);
            o1.y = fmaxf(di * accB[5] + dd * bf2f(dh.z >> 16), 0.f);
            o1.z = fmaxf(di * accB[6] + dd * bf2f(dh.w & 0xffff), 0.f);
            o1.w = fmaxf(di * accB[7] + dd * bf2f(dh.w >> 16), 0.f);
            float* op = out + (size_t)(NSRC + c1) * DIM + ql * 8;
            *(float4*)op = o0;
            *(float4*)(op + 4) = o1;
        }
    }
}

extern "C" void kernel_launch(void* const* d_in, const int* in_sizes, int n_in,
                              void* d_out, int out_size, void* d_ws, size_t ws_size,
                              hipStream_t stream) {
    const int* ei     = (const int*)d_in[0];    // [2, E] int32
    const float* xsrc = (const float*)d_in[1];  // [NSRC, 128]
    const float* xtgt = (const float*)d_in[2];  // [NTGT, 128]
    const float* W    = (const float*)d_in[3];  // [128, 128]
    float* out = (float*)d_out;                 // [NTOT, 128]

    const int* row = ei;
    const int* col = ei + NEDGE;

    char* ws = (char*)d_ws;
    unsigned short* h  = (unsigned short*)ws;  ws += (size_t)NTOT * DIM * 2;   // 25.6 MB
    unsigned short* Wt = (unsigned short*)ws;  ws += DIM * DIM * 2;            // 32 KB
    unsigned* part = (unsigned*)ws;            ws += (size_t)NBUCK * BCAP * 4; // 4.8 MB
    int* bcnt = (int*)ws;                      ws += NBUCK * BPAD * 4;         // 50 KB

    k_prep<<<64, 256, 0, stream>>>(W, Wt, bcnt);
    k_front<<<FGRID, BLK, 0, stream>>>(row, col, bcnt, part, xsrc, xtgt, Wt, h, out);
    k_back<<<NBUCK, BLK, 0, stream>>>(bcnt, part, h, out);
}

// Round 8
// 158.822 us; speedup vs baseline: 1.2403x; 1.0367x over previous
//
#include <hip/hip_runtime.h>
#include <hip/hip_bf16.h>
#include <math.h>

#define NSRC 50000
#define NTGT 50000
#define NTOT 100000
#define NEDGE 800000
#define DIM 128

#define NBUCK 782       // buckets of 64 targets (49999>>6 = 781)
#define BCAP 1536       // max edges/bucket (mean 1024, sigma 32 -> +16 sigma)
#define BPAD 16         // bcnt stride (ints): one 64B line per bucket counter
#define BLK 512         // 8 waves per block
#define EPT 16          // edges per thread in partition path (512*16 = 8192)
#define EPB 8192        // edges per partition block
#define PBLK 98         // ceil(800000 / 8192): 98*782 = 77K global atomics
#define GEMM_GRID 782   // ceil(100000 / 128) : 128 nodes per gemm block
#define FGRID (PBLK + GEMM_GRID)  // partition blocks FIRST (bid < PBLK)

typedef __attribute__((ext_vector_type(8))) short short8;
typedef __attribute__((ext_vector_type(4))) float float4v;

union U8 { short8 s; uint4 u; };

__device__ __forceinline__ unsigned short f2bf(float f) {
    unsigned u = __float_as_uint(f);
    unsigned r = (u + 0x7FFFu + ((u >> 16) & 1u)) >> 16;  // RNE
    return (unsigned short)r;
}
__device__ __forceinline__ float bf2f(unsigned us) {
    return __uint_as_float(us << 16);
}
// packed RNE f32x2 -> bf16x2 (v_cvt_pk_bf16_f32)
__device__ __forceinline__ unsigned pkbf(float lo, float hi) {
    __hip_bfloat162 b = __float22bfloat162_rn(make_float2(lo, hi));
    return *(unsigned*)&b;
}

// ---------------- prep: W -> Wt (bf16, MFMA-fragment order) + zero bcnt ---
// Wt linear idx = ((t*4+s)*64 + lane)*8 + j  ->  W[(s*32+qd*8+j)][t*16+nl]
__global__ __launch_bounds__(256) void k_prep(const float* __restrict__ W,
                                              unsigned short* __restrict__ Wt,
                                              int* __restrict__ bcnt) {
    int i = blockIdx.x * 256 + threadIdx.x;  // grid = 64 blocks -> i < 16384
    if (i < NBUCK * BPAD) bcnt[i] = 0;
    int j = i & 7, lane = (i >> 3) & 63, ts = i >> 9;
    int t = ts >> 2, s = ts & 3;
    int nl = lane & 15, qd = lane >> 4;
    Wt[i] = f2bf(W[(s * 32 + qd * 8 + j) * DIM + (t * 16 + nl)]);
}

// ---------------- fused: edge partition (bid < 98) + GEMM (rest) ----------
// partition: 8192 edges/block, 98 blocks at grid FRONT -> all launch early,
// 77K global reserve atomics (4x fewer than 391-block version).
// gemm: 8 waves x 16 nodes = 128 nodes/block, one 32KB fragment-ordered Bs
// fill per block (straight copy, conflict-free b128 reads).
__global__ __launch_bounds__(BLK) void k_front(const int* __restrict__ row,
                                               const int* __restrict__ col,
                                               int* __restrict__ bcnt,
                                               unsigned* __restrict__ part,
                                               const float* __restrict__ xsrc,
                                               const float* __restrict__ xtgt,
                                               const unsigned short* __restrict__ Wt,
                                               unsigned short* __restrict__ h,
                                               float* __restrict__ out) {
    __shared__ union SM {
        struct { int hist[NBUCK]; int runbase[NBUCK]; int cur[NBUCK]; } p;
        unsigned short Bs[DIM * DIM];  // 32 KB -> 4 blocks/CU
    } sm;

    const int tid = threadIdx.x;
    const int bid = blockIdx.x;

    if (bid < PBLK) {
        // ---------------- partition path ----------------
        for (int i = tid; i < NBUCK; i += BLK) sm.p.hist[i] = 0;
        __syncthreads();

        int e0 = bid * EPB + tid * EPT;
        bool valid = (e0 + EPT <= NEDGE);  // 800000%16==0 -> all-or-nothing
        int c[EPT], r[EPT];
        if (valid) {
#pragma unroll
            for (int v = 0; v < 4; ++v) {
                *(int4*)&c[4 * v] = *(const int4*)(col + e0 + 4 * v);
                *(int4*)&r[4 * v] = *(const int4*)(row + e0 + 4 * v);
            }
#pragma unroll
            for (int i = 0; i < EPT; ++i) atomicAdd(&sm.p.hist[c[i] >> 6], 1);
        }
        __syncthreads();
        for (int i = tid; i < NBUCK; i += BLK) {
            sm.p.runbase[i] = atomicAdd(&bcnt[i * BPAD], sm.p.hist[i]);  // reserve run
            sm.p.cur[i] = 0;
        }
        __syncthreads();
        if (valid) {
#pragma unroll
            for (int i = 0; i < EPT; ++i) {
                int q = c[i] >> 6;
                int pos = sm.p.runbase[q] + atomicAdd(&sm.p.cur[q], 1);
                part[q * BCAP + pos] = (unsigned)r[i] | ((unsigned)(c[i] & 63) << 16);
            }
        }
        return;
    }

    // ---------------- gemm path ----------------
    const int gb = bid - PBLK;  // 0..GEMM_GRID-1

    // Wt is already fragment-ordered: straight 32 KB copy, conflict-free
    for (int idx = tid; idx < 2048; idx += BLK)
        ((uint4*)sm.Bs)[idx] = ((const uint4*)Wt)[idx];

    const int wave = tid >> 6, lane = tid & 63;
    const int nl = lane & 15, quad = lane >> 4;

    // prefetch x fragments (issued before the Bs barrier)
    int node = gb * 128 + wave * 16 + nl;
    int mc = (node < NTOT) ? node : (NTOT - 1);  // clamp tail loads
    const float* xrow = (mc < NSRC) ? (xsrc + (size_t)mc * DIM)
                                    : (xtgt + (size_t)(mc - NSRC) * DIM);
    float4 a[8];
#pragma unroll
    for (int s = 0; s < 4; ++s) {
        a[2 * s]     = *(const float4*)(xrow + s * 32 + quad * 8);
        a[2 * s + 1] = *(const float4*)(xrow + s * 32 + quad * 8 + 4);
    }
    __syncthreads();  // Bs ready

    float4v acc[8];
#pragma unroll
    for (int t = 0; t < 8; ++t) acc[t] = (float4v){0.f, 0.f, 0.f, 0.f};

#pragma unroll
    for (int s = 0; s < 4; ++s) {
        U8 af;
        af.u.x = pkbf(a[2 * s].x, a[2 * s].y);
        af.u.y = pkbf(a[2 * s].z, a[2 * s].w);
        af.u.z = pkbf(a[2 * s + 1].x, a[2 * s + 1].y);
        af.u.w = pkbf(a[2 * s + 1].z, a[2 * s + 1].w);
#pragma unroll
        for (int t = 0; t < 8; ++t) {
            short8 bf = *(const short8*)&sm.Bs[((t * 4 + s) * 64 + lane) * 8];
            acc[t] = __builtin_amdgcn_mfma_f32_16x16x32_bf16(bf, af.s, acc[t], 0, 0, 0);
        }
    }

    if (node < NTOT) {
        unsigned short* hp = h + (size_t)node * DIM + quad * 4;
        float* op = out + (size_t)node * DIM + quad * 4;
        bool isrc = (node < NSRC);
#pragma unroll
        for (int t = 0; t < 8; ++t) {
            uint2 p;
            p.x = pkbf(acc[t][0], acc[t][1]);
            p.y = pkbf(acc[t][2], acc[t][3]);
            *(uint2*)(hp + t * 16) = p;
            if (isrc) {  // source nodes: deg=1 -> out = relu(h), fp32 acc
                float4 o;
                o.x = fmaxf(acc[t][0], 0.f);
                o.y = fmaxf(acc[t][1], 0.f);
                o.z = fmaxf(acc[t][2], 0.f);
                o.w = fmaxf(acc[t][3], 0.f);
                *(float4*)(op + t * 16) = o;
            }
        }
    }
}

// ---------------- per-bucket sort (LDS) + 4-way target gather-reduce ------
// 64-target buckets, 512 thr: wave w owns targets w*8..w*8+7 as 2 groups of
// 4 concurrent targets (named accA..accD, static indexing) -> up to 16
// independent gather loads in flight per lane. Quarter-wave per edge.
// Per-target edge order identical to serial version (edge 4k+qd per quad).
__global__ __launch_bounds__(BLK) void k_back(const int* __restrict__ bcnt,
                                              const unsigned* __restrict__ part,
                                              const unsigned short* __restrict__ h,
                                              float* __restrict__ out) {
    __shared__ unsigned ebuf[BCAP];       // 6 KB
    __shared__ unsigned short srt[BCAP];  // 3 KB
    __shared__ int hist[64], bufA[64], bufB[64], cur[64], st[64];

    int q = blockIdx.x, tid = threadIdx.x;
    int n = bcnt[q * BPAD];
    int base = q * BCAP;

    if (tid < 64) hist[tid] = 0;
    __syncthreads();
    for (int i = tid; i < n; i += BLK) {
        unsigned p = part[base + i];
        ebuf[i] = p;
        atomicAdd(&hist[p >> 16], 1);
    }
    __syncthreads();

    // exclusive scan of hist[64] (first 64 threads, double-buffered)
    if (tid < 64) bufA[tid] = hist[tid];
    int* src = bufA; int* dst = bufB;
    for (int d = 1; d < 64; d <<= 1) {
        __syncthreads();
        if (tid < 64) dst[tid] = src[tid] + ((tid >= d) ? src[tid - d] : 0);
        int* tp = src; src = dst; dst = tp;
    }
    __syncthreads();
    if (tid < 64) {
        int excl = src[tid] - hist[tid];
        cur[tid] = excl;
        st[tid] = excl;
    }
    __syncthreads();
    for (int i = tid; i < n; i += BLK) {
        unsigned p = ebuf[i];
        int pos = atomicAdd(&cur[p >> 16], 1);
        srt[pos] = (unsigned short)(p & 0xffffu);
    }
    __syncthreads();

    // ---------------- reduce: 2 groups of 4 concurrent targets ------------
    int w = tid >> 6, lane = tid & 63;
    int qd = lane >> 4, ql = lane & 15;  // quad owns one edge; 16 lanes x 16B
    int cl0 = w * 8;                     // wave's first local target

#define GATHER(ACC, NN, SS)                                                   \
    if (e < NN) {                                                             \
        int r = (int)srt[SS + e];                                             \
        uint4 d = *(const uint4*)(h + (size_t)r * DIM + ql * 8);              \
        ACC[0] += bf2f(d.x & 0xffff); ACC[1] += bf2f(d.x >> 16);              \
        ACC[2] += bf2f(d.y & 0xffff); ACC[3] += bf2f(d.y >> 16);              \
        ACC[4] += bf2f(d.z & 0xffff); ACC[5] += bf2f(d.z >> 16);              \
        ACC[6] += bf2f(d.w & 0xffff); ACC[7] += bf2f(d.w >> 16);              \
    }

#define WRITEOUT(ACC, NN, CL)                                                 \
    {                                                                         \
        _Pragma("unroll")                                                     \
        for (int i = 0; i < 8; ++i) {                                         \
            ACC[i] += __shfl_xor(ACC[i], 16, 64);                             \
            ACC[i] += __shfl_xor(ACC[i], 32, 64);                             \
        }                                                                     \
        int cgl = q * 64 + (CL);                                              \
        if (qd == 0 && cgl < NTGT) {                                          \
            float di = rsqrtf(1.0f + (float)NN);                              \
            float dd = di * di;                                               \
            uint4 dh = *(const uint4*)(h + (size_t)(NSRC + cgl) * DIM + ql * 8); \
            float4 o0, o1;                                                    \
            o0.x = fmaxf(di * ACC[0] + dd * bf2f(dh.x & 0xffff), 0.f);        \
            o0.y = fmaxf(di * ACC[1] + dd * bf2f(dh.x >> 16), 0.f);           \
            o0.z = fmaxf(di * ACC[2] + dd * bf2f(dh.y & 0xffff), 0.f);        \
            o0.w = fmaxf(di * ACC[3] + dd * bf2f(dh.y >> 16), 0.f);           \
            o1.x = fmaxf(di * ACC[4] + dd * bf2f(dh.z & 0xffff), 0.f);        \
            o1.y = fmaxf(di * ACC[5] + dd * bf2f(dh.z >> 16), 0.f);           \
            o1.z = fmaxf(di * ACC[6] + dd * bf2f(dh.w & 0xffff), 0.f);        \
            o1.w = fmaxf(di * ACC[7] + dd * bf2f(dh.w >> 16), 0.f);           \
            float* op = out + (size_t)(NSRC + cgl) * DIM + ql * 8;            \
            *(float4*)op = o0;                                                \
            *(float4*)(op + 4) = o1;                                          \
        }                                                                     \
    }

    for (int g = 0; g < 2; ++g) {
        int c0 = cl0 + g * 4;
        int nA = hist[c0],     sA = st[c0];
        int nB = hist[c0 + 1], sB = st[c0 + 1];
        int nC = hist[c0 + 2], sC = st[c0 + 2];
        int nD = hist[c0 + 3], sD = st[c0 + 3];

        float accA[8], accB[8], accC[8], accD[8];
#pragma unroll
        for (int i = 0; i < 8; ++i) {
            accA[i] = 0.f; accB[i] = 0.f; accC[i] = 0.f; accD[i] = 0.f;
        }

        int m1 = (nA > nB) ? nA : nB;
        int m2 = (nC > nD) ? nC : nD;
        int mx = (m1 > m2) ? m1 : m2;
        int itn = (mx + 3) >> 2;
        for (int k = 0; k < itn; ++k) {
            int e = 4 * k + qd;
            GATHER(accA, nA, sA)
            GATHER(accB, nB, sB)
            GATHER(accC, nC, sC)
            GATHER(accD, nD, sD)
        }

        WRITEOUT(accA, nA, c0)
        WRITEOUT(accB, nB, c0 + 1)
        WRITEOUT(accC, nC, c0 + 2)
        WRITEOUT(accD, nD, c0 + 3)
    }
#undef GATHER
#undef WRITEOUT
}

extern "C" void kernel_launch(void* const* d_in, const int* in_sizes, int n_in,
                              void* d_out, int out_size, void* d_ws, size_t ws_size,
                              hipStream_t stream) {
    const int* ei     = (const int*)d_in[0];    // [2, E] int32
    const float* xsrc = (const float*)d_in[1];  // [NSRC, 128]
    const float* xtgt = (const float*)d_in[2];  // [NTGT, 128]
    const float* W    = (const float*)d_in[3];  // [128, 128]
    float* out = (float*)d_out;                 // [NTOT, 128]

    const int* row = ei;
    const int* col = ei + NEDGE;

    char* ws = (char*)d_ws;
    unsigned short* h  = (unsigned short*)ws;  ws += (size_t)NTOT * DIM * 2;   // 25.6 MB
    unsigned short* Wt = (unsigned short*)ws;  ws += DIM * DIM * 2;            // 32 KB
    unsigned* part = (unsigned*)ws;            ws += (size_t)NBUCK * BCAP * 4; // 4.8 MB
    int* bcnt = (int*)ws;                      ws += NBUCK * BPAD * 4;         // 50 KB

    k_prep<<<64, 256, 0, stream>>>(W, Wt, bcnt);
    k_front<<<FGRID, BLK, 0, stream>>>(row, col, bcnt, part, xsrc, xtgt, Wt, h, out);
    k_back<<<NBUCK, BLK, 0, stream>>>(bcnt, part, h, out);
}